// Round 1
// baseline (949.562 us; speedup 1.0000x reference)
//
#include <hip/hip_runtime.h>

// Problem constants
#define BB 16384
#define NN 32
#define DD 256
#define CC 128
#define HH 8
#define LDSTR 260          // padded row stride (floats): 260%32=4 -> conflict-free, 16B-aligned
#define ALPHA 0.2f

// ---------------------------------------------------------------------------
// Kernel 1: KaT[which][h][d] = sum_c kernel[d][c] * attn[0][h][which*C + c]
// which=0 -> a_src projection, which=1 -> a_dst projection. 4096 outputs.
// ---------------------------------------------------------------------------
__global__ __launch_bounds__(256) void ka_kernel(const float* __restrict__ kern,
                                                 const float* __restrict__ attn,
                                                 float* __restrict__ KaT) {
    int i = blockIdx.x * 256 + threadIdx.x;   // 0..4095  (grid = 16)
    int which = i >> 11;
    int r = i & 2047;
    int h = r >> 8;
    int d = r & 255;
    const float* krow = kern + d * CC;
    const float* arow = attn + h * (2 * CC) + which * CC;
    float s = 0.f;
#pragma unroll 8
    for (int c = 0; c < CC; ++c) s += krow[c] * arow[c];
    KaT[i] = s;   // layout: [which*2048 + h*256 + d]
}

// ---------------------------------------------------------------------------
// Kernel 2: fully fused per-node attention. One block per node b.
//   scores[n,h] = node.Ka_src[h] + neigh[n].Ka_dst[h]  -> leaky -> softmax(n)
//   agg[h,d]    = sum_n coef[h,n] * neigh[n,d]
//   z[h,c]      = sum_d agg[h,d] * kernel[d,c] + bias
// LDS budget: 13248 floats = 52992 B -> 3 blocks/CU.
// ---------------------------------------------------------------------------
__global__ __launch_bounds__(256) void gat_kernel(const float* __restrict__ node,
                                                  const float* __restrict__ neigh,
                                                  const float* __restrict__ kern,
                                                  const float* __restrict__ bias,
                                                  const float* __restrict__ KaT,
                                                  float* __restrict__ out) {
    const int b = blockIdx.x;
    const int t = threadIdx.x;

    __shared__ __align__(16) float smem[13248];
    float* sNeigh   = smem;            // 32 x 260 = 8320 floats
    float* sKas     = smem + 8320;     // 8 x 260 = 2080 floats (Ka_src, transposed [h][d])
    float* sAgg     = smem + 8320;     // OVERLAY: 8 x 256 = 2048 floats (after phase B done)
    float* sKad     = smem + 10400;    // 8 x 260 = 2080 floats (Ka_dst)
    float* sNode    = smem + 12480;    // 256
    float* sScores  = smem + 12736;    // 32 x 8  [n*8+h]
    float* sCoef    = smem + 12992;    // 8 x 32  [h*32+n]

    // ---- Phase A: stage inputs ----
    const float4* nb4 = (const float4*)(neigh) + (size_t)b * (NN * DD / 4);
#pragma unroll
    for (int k = 0; k < 8; ++k) {
        int j  = k * 256 + t;          // float4 index, 0..2047
        int n  = j >> 6;
        int d4 = j & 63;
        ((float4*)(sNeigh + n * LDSTR))[d4] = nb4[j];
    }
    const float4* ka4 = (const float4*)KaT;
#pragma unroll
    for (int k = 0; k < 2; ++k) {
        int j4 = k * 256 + t;          // 0..511 (2048 floats)
        int h  = j4 >> 6;
        int d4 = j4 & 63;
        ((float4*)(sKas + h * LDSTR))[d4] = ka4[j4];
        ((float4*)(sKad + h * LDSTR))[d4] = ka4[512 + j4];
    }
    sNode[t] = node[(size_t)b * DD + t];
    __syncthreads();

    // ---- Phase B: scores (one thread per (n,h)) ----
    {
        int n = t >> 3, h = t & 7;
        const float4* nr = (const float4*)(sNeigh + n * LDSTR);
        const float4* kd = (const float4*)(sKad + h * LDSTR);
        const float4* ks = (const float4*)(sKas + h * LDSTR);
        const float4* nd = (const float4*)sNode;
        float s = 0.f;
#pragma unroll 8
        for (int d4 = 0; d4 < 64; ++d4) {
            float4 a = nr[d4], w = kd[d4], c = nd[d4], e = ks[d4];
            s += a.x * w.x + a.y * w.y + a.z * w.z + a.w * w.w;
            s += c.x * e.x + c.y * e.y + c.z * e.z + c.w * e.w;
        }
        s = (s > 0.f) ? s : ALPHA * s;   // leaky relu
        sScores[n * 8 + h] = s;
    }
    __syncthreads();

    // ---- Phase C: softmax over n (per h), redundantly per thread ----
    {
        int n = t >> 3, h = t & 7;
        float m = -1e30f;
#pragma unroll
        for (int j = 0; j < NN; ++j) m = fmaxf(m, sScores[j * 8 + h]);
        float denom = 0.f;
#pragma unroll
        for (int j = 0; j < NN; ++j) denom += __expf(sScores[j * 8 + h] - m);
        float e = __expf(sScores[n * 8 + h] - m);
        sCoef[h * 32 + n] = e / denom;
    }
    __syncthreads();

    // ---- Phase D: agg[h][d] = sum_n coef[h][n]*neigh[n][d]; thread owns d=t ----
    {
        float acc[8] = {0.f, 0.f, 0.f, 0.f, 0.f, 0.f, 0.f, 0.f};
#pragma unroll 8
        for (int n = 0; n < NN; ++n) {
            float v = sNeigh[n * LDSTR + t];
#pragma unroll
            for (int h = 0; h < HH; ++h) acc[h] += sCoef[h * 32 + n] * v;
        }
        // sAgg overlays sKas: sKas last read in phase B (barrier since), safe.
#pragma unroll
        for (int h = 0; h < HH; ++h) sAgg[h * 256 + t] = acc[h];
    }
    __syncthreads();

    // ---- Phase E: z[h][c] = sum_d agg[h][d]*kern[d][c]; split-K across halves ----
    {
        int c = t & 127;
        int g = t >> 7;                 // 0 or 1: which half of d-range
        float acc[8] = {0.f, 0.f, 0.f, 0.f, 0.f, 0.f, 0.f, 0.f};
        int dbase = g * 128;
#pragma unroll 2
        for (int d4 = 0; d4 < 32; ++d4) {
            int d = dbase + d4 * 4;
            float kv0 = kern[(size_t)(d + 0) * CC + c];
            float kv1 = kern[(size_t)(d + 1) * CC + c];
            float kv2 = kern[(size_t)(d + 2) * CC + c];
            float kv3 = kern[(size_t)(d + 3) * CC + c];
#pragma unroll
            for (int h = 0; h < HH; ++h) {
                float4 ag = ((const float4*)(sAgg + h * 256))[g * 32 + d4];
                acc[h] += ag.x * kv0 + ag.y * kv1 + ag.z * kv2 + ag.w * kv3;
            }
        }
        // partials into LDS (reuse sNeigh region; its last read was phase D, barrier since)
        float* sP = sNeigh;
#pragma unroll
        for (int h = 0; h < HH; ++h) sP[g * 1024 + h * 128 + c] = acc[h];
    }
    __syncthreads();

    // ---- Final: combine halves + bias, vectorized store ----
    {
        const float4* sP4   = (const float4*)sNeigh;
        const float4* bias4 = (const float4*)bias;
        float4 p0 = sP4[t];
        float4 p1 = sP4[256 + t];
        float4 bv = bias4[t];
        float4 r;
        r.x = p0.x + p1.x + bv.x;
        r.y = p0.y + p1.y + bv.y;
        r.z = p0.z + p1.z + bv.z;
        r.w = p0.w + p1.w + bv.w;
        ((float4*)(out + (size_t)b * (HH * CC)))[t] = r;
    }
}

extern "C" void kernel_launch(void* const* d_in, const int* in_sizes, int n_in,
                              void* d_out, int out_size, void* d_ws, size_t ws_size,
                              hipStream_t stream) {
    const float* node  = (const float*)d_in[0];   // (B, D)
    const float* neigh = (const float*)d_in[1];   // (B, N, D)
    const float* kern  = (const float*)d_in[2];   // (D, C)
    const float* attn  = (const float*)d_in[3];   // (1, H, 2C)
    const float* bias  = (const float*)d_in[4];   // (H*C,)
    float* out = (float*)d_out;                   // (1, B, H*C)
    float* KaT = (float*)d_ws;                    // 4096 floats scratch

    hipLaunchKernelGGL(ka_kernel, dim3(16), dim3(256), 0, stream, kern, attn, KaT);
    hipLaunchKernelGGL(gat_kernel, dim3(BB), dim3(256), 0, stream,
                       node, neigh, kern, bias, KaT, out);
}

// Round 2
// 793.353 us; speedup vs baseline: 1.1969x; 1.1969x over previous
//
#include <hip/hip_runtime.h>

#define BB 16384
#define NN 32
#define DD 256
#define CC 128
#define HH 8
#define ALPHA 0.2f

// LDS geometry
#define SA_STRIDE 264          // bf16 elems per row (256 + 8 pad); 528 B, 16B-aligned
#define SP_STRIDE 48           // bf16 elems per neigh_pT row (32 + 16 pad); 96 B

typedef __attribute__((ext_vector_type(8))) short bf16x8;
typedef __attribute__((ext_vector_type(4))) float f32x4;

// fp32 -> bf16 bits, round-to-nearest-even
__device__ __forceinline__ unsigned short f2b(float x) {
    unsigned int u = __float_as_uint(x);
    return (unsigned short)((u + 0x7fffu + ((u >> 16) & 1u)) >> 16);
}
__device__ __forceinline__ uint2 pack4(float a, float b, float c, float d) {
    uint2 r;
    r.x = (unsigned)f2b(a) | ((unsigned)f2b(b) << 16);
    r.y = (unsigned)f2b(c) | ((unsigned)f2b(d) << 16);
    return r;
}

// ---------------------------------------------------------------------------
// Prep kernel: build MFMA B-fragment-ordered constant tables in d_ws.
//  kfrag (ws+0, 65536 B):  kern bf16, frag addr ((nt*8+ks)*64+lane)*8+j
//                          value = kern[k=ks*32+(lane>>4)*8+j][c=nt*16+(lane&15)]
//  sfrag (ws+65536, 8192 B): [Kad | Kas] (256x16) same layout (single n-tile)
//                          col<8 -> Kad[k][col] = sum_c kern[k][c]*attn[col][C+c]
//                          col>=8-> Kas[k][col-8] = sum_c kern[k][c]*attn[col-8][c]
// Grid: 18 blocks x 256. Blocks 0..15 -> kfrag, 16..17 -> sfrag.
// ---------------------------------------------------------------------------
__global__ __launch_bounds__(256) void prep_kernel(const float* __restrict__ kern,
                                                   const float* __restrict__ attn,
                                                   unsigned short* __restrict__ kfrag,
                                                   unsigned short* __restrict__ sfrag) {
    if (blockIdx.x < 16) {
        int tid = blockIdx.x * 256 + threadIdx.x;    // 0..4095
        int nt   = tid >> 9;
        int ks   = (tid >> 6) & 7;
        int lane = tid & 63;
        int q    = lane >> 4;
        int cc   = lane & 15;
        int c    = nt * 16 + cc;
        unsigned short v[8];
#pragma unroll
        for (int j = 0; j < 8; ++j) {
            int k = ks * 32 + q * 8 + j;
            v[j] = f2b(kern[k * CC + c]);
        }
        uint4* dst = (uint4*)(kfrag + ((size_t)(nt * 8 + ks) * 64 + lane) * 8);
        uint4 pk;
        pk.x = (unsigned)v[0] | ((unsigned)v[1] << 16);
        pk.y = (unsigned)v[2] | ((unsigned)v[3] << 16);
        pk.z = (unsigned)v[4] | ((unsigned)v[5] << 16);
        pk.w = (unsigned)v[6] | ((unsigned)v[7] << 16);
        *dst = pk;
    } else {
        int sid = (blockIdx.x - 16) * 256 + threadIdx.x;  // 0..511
        int ks   = sid >> 6;
        int lane = sid & 63;
        int q    = lane >> 4;
        int cc   = lane & 15;
        unsigned short v[8];
#pragma unroll
        for (int j = 0; j < 8; ++j) {
            int k = ks * 32 + q * 8 + j;
            const float* krow = kern + (size_t)k * CC;
            const float* arow = (cc < 8) ? (attn + cc * (2 * CC) + CC)
                                         : (attn + (cc - 8) * (2 * CC));
            float s0 = 0.f, s1 = 0.f;
#pragma unroll 4
            for (int c = 0; c < CC; c += 2) {
                s0 += krow[c] * arow[c];
                s1 += krow[c + 1] * arow[c + 1];
            }
            v[j] = f2b(s0 + s1);
        }
        uint4* dst = (uint4*)(sfrag + ((size_t)ks * 64 + lane) * 8);
        uint4 pk;
        pk.x = (unsigned)v[0] | ((unsigned)v[1] << 16);
        pk.y = (unsigned)v[2] | ((unsigned)v[3] << 16);
        pk.z = (unsigned)v[4] | ((unsigned)v[5] << 16);
        pk.w = (unsigned)v[6] | ((unsigned)v[7] << 16);
        *dst = pk;
    }
}

// ---------------------------------------------------------------------------
// Main fused kernel: one block per node. 256 threads = 4 waves.
//   sA rows 0..31 = neigh (bf16), row 32 = node, rows 33..47 garbage (ignored)
//   scores  : A(rows 0..32) @ [Kad|Kas]  -> MFMA (3 M-tiles, waves 0..2)
//   neigh_p : A(rows 0..31) @ kern       -> MFMA (2 M-tiles x 8 N-tiles), ->sP^T bf16
//   softmax : fp32 VALU, coef -> B-fragment layout (cfrag)
//   z^T     : sP^T @ cfrag               -> MFMA (8 M-tiles), +bias, float4 store
// LDS total 39712 B -> 4 blocks/CU.
// ---------------------------------------------------------------------------
__global__ __launch_bounds__(256, 4) void gat_kernel(const float* __restrict__ node,
                                                     const float* __restrict__ neigh,
                                                     const float* __restrict__ bias,
                                                     const unsigned short* __restrict__ kfrag,
                                                     const unsigned short* __restrict__ sfrag,
                                                     float* __restrict__ out) {
    const int b    = blockIdx.x;
    const int t    = threadIdx.x;
    const int lane = t & 63;
    const int wave = t >> 6;
    const int q    = lane >> 4;
    const int m15  = lane & 15;

    __shared__ __align__(16) char smem[39712];
    unsigned short* sA    = (unsigned short*)smem;            // 48*264*2 = 25344 B
    unsigned short* sP    = (unsigned short*)(smem + 25344);  // 128*48*2 = 12288 B
    unsigned short* cfrag = (unsigned short*)(smem + 37632);  // 512*2    = 1024 B
    float*          sDst  = (float*)(smem + 38656);           // 32*8*4   = 1024 B
    float*          sSrc  = (float*)(smem + 39680);           // 8*4      = 32 B

    // ---- Stage: 33 rows x 256 fp32 -> bf16 in sA ----
    {
        const float4* nb4 = (const float4*)(neigh + (size_t)b * (NN * DD));
        const float4* nd4 = (const float4*)(node + (size_t)b * DD);
        for (int j = t; j < 33 * 64; j += 256) {
            int row = j >> 6, d4 = j & 63;
            float4 v = (row < 32) ? nb4[row * 64 + d4] : nd4[d4];
            *(uint2*)(sA + row * SA_STRIDE + d4 * 4) = pack4(v.x, v.y, v.z, v.w);
        }
    }
    __syncthreads();

    // ---- Phase 3: scores via MFMA. waves 0..2 take M-tile = wave ----
    if (wave < 3) {
        const int mt = wave;
        f32x4 acc = {0.f, 0.f, 0.f, 0.f};
        const unsigned short* abase = sA + (mt * 16 + m15) * SA_STRIDE + q * 8;
#pragma unroll
        for (int ks = 0; ks < 8; ++ks) {
            bf16x8 bfr = *(const bf16x8*)(sfrag + ((size_t)ks * 64 + lane) * 8);
            bf16x8 afr = *(const bf16x8*)(abase + ks * 32);
            acc = __builtin_amdgcn_mfma_f32_16x16x32_bf16(afr, bfr, acc, 0, 0, 0);
        }
#pragma unroll
        for (int r = 0; r < 4; ++r) {
            int row = mt * 16 + q * 4 + r;
            if (row < 32 && m15 < 8) sDst[row * 8 + m15] = acc[r];
            if (row == 32 && m15 >= 8) sSrc[m15 - 8] = acc[r];
        }
    }

    // ---- Phase 1: neigh_p via MFMA; each wave: N-tiles {2w, 2w+1}, M-tiles 0..1 ----
#pragma unroll
    for (int nti = 0; nti < 2; ++nti) {
        const int nt = wave * 2 + nti;
        bf16x8 kb[8];
#pragma unroll
        for (int ks = 0; ks < 8; ++ks)
            kb[ks] = *(const bf16x8*)(kfrag + ((size_t)(nt * 8 + ks) * 64 + lane) * 8);
#pragma unroll
        for (int mt = 0; mt < 2; ++mt) {
            f32x4 acc = {0.f, 0.f, 0.f, 0.f};
            const unsigned short* abase = sA + (mt * 16 + m15) * SA_STRIDE + q * 8;
#pragma unroll
            for (int ks = 0; ks < 8; ++ks) {
                bf16x8 afr = *(const bf16x8*)(abase + ks * 32);
                acc = __builtin_amdgcn_mfma_f32_16x16x32_bf16(afr, kb[ks], acc, 0, 0, 0);
            }
            // transpose-store: lane col c = nt*16+m15 fixed; 4 consecutive n
            int c  = nt * 16 + m15;
            int n0 = mt * 16 + q * 4;
            *(uint2*)(sP + c * SP_STRIDE + n0) = pack4(acc[0], acc[1], acc[2], acc[3]);
        }
    }
    __syncthreads();

    // ---- Phase 4: softmax over n (fp32). thread t -> h = t>>5, n = t&31 ----
    {
        int h = t >> 5, n = t & 31;
        float sc = sSrc[h] + sDst[n * 8 + h];
        sc = fmaxf(sc, ALPHA * sc);              // leaky relu
        float m = sc;
#pragma unroll
        for (int off = 16; off >= 1; off >>= 1) m = fmaxf(m, __shfl_xor(m, off, 32));
        float e = expf(sc - m);
        float den = e;
#pragma unroll
        for (int off = 16; off >= 1; off >>= 1) den += __shfl_xor(den, off, 32);
        float coef = e / den;
        int l1 = (n >> 3) * 16 + h;              // cols 0..7: coef
        int jj = n & 7;
        cfrag[l1 * 8 + jj] = f2b(coef);
        cfrag[(l1 + 8) * 8 + jj] = 0;            // cols 8..15: zero
    }
    __syncthreads();

    // ---- Phase 5: z^T = sP^T @ coef. wave handles M-tiles {2w, 2w+1} ----
    {
        bf16x8 cb = *(const bf16x8*)(cfrag + (size_t)lane * 8);
        f32x4 zero = {0.f, 0.f, 0.f, 0.f};
#pragma unroll
        for (int i = 0; i < 2; ++i) {
            int mt5 = wave * 2 + i;
            bf16x8 afr = *(const bf16x8*)(sP + (mt5 * 16 + m15) * SP_STRIDE + q * 8);
            f32x4 acc = __builtin_amdgcn_mfma_f32_16x16x32_bf16(afr, cb, zero, 0, 0, 0);
            if (m15 < 8) {                        // col = h; cols 8..15 are zero-pad
                int h  = m15;
                int c0 = mt5 * 16 + q * 4;
                float4 bv = *(const float4*)(bias + h * CC + c0);
                float4 r;
                r.x = acc[0] + bv.x;
                r.y = acc[1] + bv.y;
                r.z = acc[2] + bv.z;
                r.w = acc[3] + bv.w;
                *(float4*)(out + (size_t)b * (HH * CC) + h * CC + c0) = r;
            }
        }
    }
}

extern "C" void kernel_launch(void* const* d_in, const int* in_sizes, int n_in,
                              void* d_out, int out_size, void* d_ws, size_t ws_size,
                              hipStream_t stream) {
    const float* node  = (const float*)d_in[0];   // (B, D)
    const float* neigh = (const float*)d_in[1];   // (B, N, D)
    const float* kern  = (const float*)d_in[2];   // (D, C)
    const float* attn  = (const float*)d_in[3];   // (1, H, 2C)
    const float* bias  = (const float*)d_in[4];   // (H*C,)
    float* out = (float*)d_out;                   // (1, B, H*C)

    unsigned short* kfrag = (unsigned short*)d_ws;                  // 65536 B
    unsigned short* sfrag = (unsigned short*)((char*)d_ws + 65536); // 8192 B

    hipLaunchKernelGGL(prep_kernel, dim3(18), dim3(256), 0, stream, kern, attn, kfrag, sfrag);
    hipLaunchKernelGGL(gat_kernel, dim3(BB), dim3(256), 0, stream,
                       node, neigh, bias, kfrag, sfrag, out);
}